// Round 18
// baseline (29.064 us; speedup 1.0000x reference)
//
#include <hip/hip_runtime.h>
#include <math.h>

namespace {

constexpr int B_ = 8, W_ = 64, T_ = 256, D_ = 256;

typedef _Float16 h2 __attribute__((ext_vector_type(2)));
typedef _Float16 h8 __attribute__((ext_vector_type(8)));
typedef float f32x4 __attribute__((ext_vector_type(4)));
typedef __fp16 fp16v2 __attribute__((ext_vector_type(2)));

// -------- workspace layout (float offsets) --------
constexpr int WS_ST    = 0;       // B*T
constexpr int WS_SUMT  = 2048;
constexpr int WS_SST   = 4096;
constexpr int WS_SW    = 6144;    // B*W
constexpr int WS_SUMW  = 6656;
constexpr int WS_SSW   = 7168;
constexpr int WS_SG    = 7680;    // B
constexpr int WS_SUMG  = 7688;
constexpr int WS_SSG   = 7696;
constexpr int WS_C0    = 7704;
constexpr int WS_C1    = 7705;
constexpr int WS_GFEAT = 7712;    // B*D
constexpr int WS_TPP   = 9760;    // 128 * 256
constexpr int WS_WPP   = 42528;   // 32 * 256
constexpr int WS_PK    = 665120;  // packed weights (16B-aligned)

// ---- packed-weight offsets (uint4 units) ----
constexpr int FM_TE1  = 0;
constexpr int FM_TE2  = 1024;
constexpr int FM_FT   = 9216;
constexpr int FM_WLE1 = 17408;
constexpr int FM_WLE2 = 18432;
constexpr int FM_WPE1 = 26624;
constexpr int FM_WPE2 = 27648;
constexpr int FM_FW   = 35840;
constexpr int FM_END  = 52224;
constexpr int PM_G1   = 52224;
constexpr int PM_G2   = 54272;
constexpr int PM_VU1  = 62464;   // VU/VC packed by enc prologue (blocks 0..95)
constexpr int PM_VC1  = 87040;
constexpr int PK_ENC  = 62464;   // pack_kernel covers [0, PK_ENC): 244 blocks
constexpr int PK_HEADN = 49152;  // VU+VC items = 96 blocks x 512 threads

__device__ __forceinline__ float wave_sum(float v) {
#pragma unroll
  for (int m = 32; m > 0; m >>= 1) v += __shfl_xor(v, m, 64);
  return v;
}

__device__ __forceinline__ float red16(float v) {
  v += __shfl_xor(v, 1, 64);
  v += __shfl_xor(v, 2, 64);
  v += __shfl_xor(v, 4, 64);
  v += __shfl_xor(v, 8, 64);
  return v;
}

__device__ __forceinline__ unsigned pkrtz_u(float a, float b) {
  fp16v2 p = __builtin_amdgcn_cvt_pkrtz(a, b);
  return __builtin_bit_cast(unsigned, p);
}

__device__ __forceinline__ float fdot2u(unsigned x, unsigned w, float c) {
#if __has_builtin(__builtin_amdgcn_fdot2)
  return __builtin_amdgcn_fdot2(__builtin_bit_cast(h2, x),
                                __builtin_bit_cast(h2, w), c, false);
#else
  h2 a = __builtin_bit_cast(h2, x);
  h2 b = __builtin_bit_cast(h2, w);
  float r = fmaf((float)a.x, (float)b.x, c);
  return fmaf((float)a.y, (float)b.y, r);
#endif
}

template <int R, int G>
__device__ __forceinline__ void gemmp(const uint4* __restrict__ Wp,
                                      const uint4* xp, int xs, int d,
                                      float* acc) {
#pragma unroll
  for (int r = 0; r < R; ++r) acc[r] = 0.f;
#pragma unroll 4
  for (int g = 0; g < G; ++g) {
    uint4 w = Wp[g * 256 + d];
#pragma unroll
    for (int r = 0; r < R; ++r) {
      uint4 x = xp[r * xs + g];
      acc[r] = fdot2u(x.x, w.x, acc[r]);
      acc[r] = fdot2u(x.y, w.y, acc[r]);
      acc[r] = fdot2u(x.z, w.z, acc[r]);
      acc[r] = fdot2u(x.w, w.w, acc[r]);
    }
  }
}

template <int R>
__device__ __forceinline__ void shfl_pack(const float* v, unsigned* dst,
                                          int stride, int d) {
#pragma unroll
  for (int r = 0; r < R; ++r) {
    float p = __shfl_xor(v[r], 1, 64);
    unsigned pk = (d & 1) ? pkrtz_u(p, v[r]) : pkrtz_u(v[r], p);
    if (!(d & 1)) dst[r * stride + (d >> 1)] = pk;
  }
}

// ---- cross-stage B-fragment prefetch (validated R9/R15) ----
template <int NT, int KS>
__device__ __forceinline__ void load_bfrags(const uint4* __restrict__ wb,
                                            int nt0, int ks0, int l,
                                            uint4* pf) {
#pragma unroll
  for (int nt = 0; nt < NT; ++nt)
#pragma unroll
    for (int ks = 0; ks < KS; ++ks)
      pf[nt * KS + ks] = wb[((ks0 + ks) * 16 + nt0 + nt) * 64 + l];
}

template <int NT, int KS, bool ACC_IN>
__device__ __forceinline__ void mfma_from(const uint4* pf, const h8* afr,
                                          f32x4* acc) {
#pragma unroll
  for (int nt = 0; nt < NT; ++nt) {
    f32x4 c;
    if (ACC_IN) c = acc[nt];
    else { c[0] = 0.f; c[1] = 0.f; c[2] = 0.f; c[3] = 0.f; }
#pragma unroll
    for (int ks = 0; ks < KS; ++ks)
      c = __builtin_amdgcn_mfma_f32_16x16x32_f16(
          afr[ks], __builtin_bit_cast(h8, pf[nt * KS + ks]), c, 0, 0, 0);
    acc[nt] = c;
  }
}

template <int NT, int KS, bool ACC_IN>
__device__ __forceinline__ void mfma_gemm(const uint4* __restrict__ wb,
                                          int nt0, int ks0, int l,
                                          const h8* afr, f32x4* acc) {
  uint4 pf[NT * KS];
  load_bfrags<NT, KS>(wb, nt0, ks0, l, pf);
  mfma_from<NT, KS, ACC_IN>(pf, afr, acc);
}

template <int KS>
__device__ __forceinline__ void lda(const _Float16* src, int row, int stride,
                                    int l4, h8* afr) {
#pragma unroll
  for (int ks = 0; ks < KS; ++ks)
    afr[ks] = *(const h8*)(src + row * stride + ks * 32 + 8 * l4);
}

template <int NT, bool RELU>
__device__ __forceinline__ void epi_store(const f32x4* acc,
                                          const float* __restrict__ bias,
                                          int c0, int dc0, int l15, int l4,
                                          _Float16* dst, int stride) {
#pragma unroll
  for (int nt = 0; nt < NT; ++nt) {
    float bv = bias[c0 + nt * 16 + l15];
    int dc = dc0 + nt * 16 + l15;
#pragma unroll
    for (int i = 0; i < 4; ++i) {
      float v = acc[nt][i] + bv;
      if (RELU) v = fmaxf(v, 0.f);
      dst[(l4 * 4 + i) * stride + dc] = (_Float16)v;
    }
  }
}

// Full-row LN across 8 waves x 2 nt; wave owns cols 32*wq.
template <bool MASKED>
__device__ __forceinline__ void ln_block8(
    f32x4* acc, const float* __restrict__ g, const float* __restrict__ bt,
    const float* __restrict__ fn_g_seg, const float* __restrict__ aw_seg,
    const float* __restrict__ mask_base, float* stA, float* stB, int wq, int l,
    int tid, float* __restrict__ pool, float* __restrict__ Sd,
    float* __restrict__ sumd, float* __restrict__ ssd) {
  const int l15 = l & 15, l4 = l >> 4;
#pragma unroll
  for (int i = 0; i < 4; ++i) {
    float s = 0.f, ss = 0.f;
#pragma unroll
    for (int nt = 0; nt < 2; ++nt) {
      float v = acc[nt][i];
      s += v;
      ss = fmaf(v, v, ss);
    }
    s = red16(s);
    ss = red16(ss);
    if (l15 == 0) {
      int row = l4 * 4 + i;
      stA[(row * 8 + wq) * 2 + 0] = s;
      stA[(row * 8 + wq) * 2 + 1] = ss;
    }
  }
  __syncthreads();
  float gg[2], bb[2], fa[2];
#pragma unroll
  for (int nt = 0; nt < 2; ++nt) {
    int c = wq * 32 + nt * 16 + l15;
    gg[nt] = g[c];
    bb[nt] = bt[c];
    fa[nt] = fn_g_seg[c] * aw_seg[c];
  }
  float pp[2] = {0.f, 0.f};
#pragma unroll
  for (int i = 0; i < 4; ++i) {
    int row = l4 * 4 + i;
    float s = 0.f, ss = 0.f;
#pragma unroll
    for (int q = 0; q < 8; ++q) {
      s += stA[(row * 8 + q) * 2];
      ss += stA[(row * 8 + q) * 2 + 1];
    }
    float mu = s * (1.f / 256.f);
    float var = ss * (1.f / 256.f) - mu * mu;
    float inv = rsqrtf(var + 1e-5f);
    float mk = MASKED ? mask_base[row] : 1.f;
    float a1 = 0.f, a2 = 0.f, a3 = 0.f;
#pragma unroll
    for (int nt = 0; nt < 2; ++nt) {
      float v = (acc[nt][i] - mu) * inv * gg[nt] + bb[nt];
      a1 = fmaf(v, fa[nt], a1);
      a2 += v;
      a3 = fmaf(v, v, a3);
      pp[nt] = fmaf(mk, v, pp[nt]);
    }
    a1 = red16(a1);
    a2 = red16(a2);
    a3 = red16(a3);
    if (l15 == 0) {
      stB[(row * 8 + wq) * 3 + 0] = a1;
      stB[(row * 8 + wq) * 3 + 1] = a2;
      stB[(row * 8 + wq) * 3 + 2] = a3;
    }
  }
#pragma unroll
  for (int nt = 0; nt < 2; ++nt) {
    pp[nt] += __shfl_xor(pp[nt], 16, 64);
    pp[nt] += __shfl_xor(pp[nt], 32, 64);
  }
  if (l < 16) {
#pragma unroll
    for (int nt = 0; nt < 2; ++nt) pool[wq * 32 + nt * 16 + l15] = pp[nt];
  }
  __syncthreads();
  if (tid < 16) {
    int row = tid;
    float sA = 0.f, sB = 0.f, sC = 0.f;
#pragma unroll
    for (int q = 0; q < 8; ++q) {
      sA += stB[(row * 8 + q) * 3 + 0];
      sB += stB[(row * 8 + q) * 3 + 1];
      sC += stB[(row * 8 + q) * 3 + 2];
    }
    Sd[row] = sA;
    sumd[row] = sB;
    ssd[row] = sC;
  }
}

// -------------------- weight pre-pack (enc region: 244 blocks) --------------
__global__ __launch_bounds__(256) void pack_kernel(
    const float* __restrict__ te_w1, const float* __restrict__ te_w2,
    const float* __restrict__ ft_w, const float* __restrict__ wle_w1,
    const float* __restrict__ wle_w2, const float* __restrict__ wpe_w1,
    const float* __restrict__ wpe_w2, const float* __restrict__ fw_w,
    const float* __restrict__ g_w1, const float* __restrict__ g_w2,
    uint4* __restrict__ dst) {
  int i = blockIdx.x * 256 + threadIdx.x;  // i < PK_ENC
  if (i < FM_END) {
    const float* src; int off, Ksrc;
    if      (i < FM_TE2)  { src = te_w1;  off = FM_TE1;  Ksrc = 32;  }
    else if (i < FM_FT)   { src = te_w2;  off = FM_TE2;  Ksrc = 256; }
    else if (i < FM_WLE1) { src = ft_w;   off = FM_FT;   Ksrc = 256; }
    else if (i < FM_WLE2) { src = wle_w1; off = FM_WLE1; Ksrc = 16;  }
    else if (i < FM_WPE1) { src = wle_w2; off = FM_WLE2; Ksrc = 256; }
    else if (i < FM_WPE2) { src = wpe_w1; off = FM_WPE1; Ksrc = 24;  }
    else if (i < FM_FW)   { src = wpe_w2; off = FM_WPE2; Ksrc = 256; }
    else                  { src = fw_w;   off = FM_FW;   Ksrc = 512; }
    int li = i - off;
    int l = li & 63, nt = (li >> 6) & 15, ks = li >> 10;
    int n = nt * 16 + (l & 15);
    int k0 = ks * 32 + 8 * (l >> 4);
    h8 v;
#pragma unroll
    for (int j = 0; j < 8; ++j) {
      int k = k0 + j;
      v[j] = (k < Ksrc) ? (_Float16)src[(size_t)k * 256 + n] : (_Float16)0.f;
    }
    dst[i] = __builtin_bit_cast(uint4, v);
  } else {
    const float* src; int off;
    if (i < PM_G2) { src = g_w1; off = PM_G1; }
    else           { src = g_w2; off = PM_G2; }
    int li = i - off;
    int g = li >> 8, d = li & 255;
    const float* p = src + (size_t)g * 8 * 256 + d;
    unsigned r[4];
#pragma unroll
    for (int j = 0; j < 4; ++j) {
      h2 pk;
      pk.x = (_Float16)p[(2 * j) * 256];
      pk.y = (_Float16)p[(2 * j + 1) * 256];
      r[j] = __builtin_bit_cast(unsigned, pk);
    }
    uint4 o;
    o.x = r[0]; o.y = r[1]; o.z = r[2]; o.w = r[3];
    dst[i] = o;
  }
}

// -------------------- fused encoders: 161 blocks x 512 threads --------------
__global__ __launch_bounds__(512) void enc_kernel(
    const float* __restrict__ task_obs, const float* __restrict__ worker_loads,
    const float* __restrict__ worker_profiles,
    const float* __restrict__ global_context,
    const float* __restrict__ valid_mask, const float* __restrict__ vu_w1,
    const float* __restrict__ vc_w1, const float* __restrict__ te_b1,
    const float* __restrict__ te_b2, const float* __restrict__ wle_b1,
    const float* __restrict__ wle_b2, const float* __restrict__ wpe_b1,
    const float* __restrict__ wpe_b2, const float* __restrict__ ft_b,
    const float* __restrict__ ft_g, const float* __restrict__ ft_bt,
    const float* __restrict__ fw_b, const float* __restrict__ fw_g,
    const float* __restrict__ fw_bt, const float* __restrict__ g_b1,
    const float* __restrict__ g_b2, const float* __restrict__ fn_g,
    const float* __restrict__ fn_b, const float* __restrict__ actor_w,
    const float* __restrict__ actor_b, float* __restrict__ ws) {
  __shared__ __align__(16) unsigned char smem[29440];
  const int tid = threadIdx.x;
  const int blk = blockIdx.x;
  const int w = tid >> 6, l = tid & 63;
  const int l15 = l & 15, l4 = l >> 4;
  // De-lockstep rotation (R10, validated): wave w owns column-tile wq.
  const int swz = ((blk >> 3) + blk) & 7;
  const int wq = (w + swz) & 7;
  uint4* wpk = (uint4*)(ws + WS_PK);
  float* stA = (float*)(smem + 26880);  // 256 floats
  float* stB = (float*)(smem + 27904);  // 384 floats

  // ---- prologue: pack VU/VC head weights (consumed only by head kernel;
  //      ordered by the kernel boundary). Explicit-compare indexing. ----
  {
    int pi = blk * 512 + tid;
    if (pi < PK_HEADN) {
      const float* src;
      int li;
      if (pi < 24576) { src = vu_w1; li = pi; }
      else            { src = vc_w1; li = pi - 24576; }
      int g = li >> 8, d = li & 255;
      const float* p = src + (size_t)g * 8 * 256 + d;
      unsigned r[4];
#pragma unroll
      for (int j = 0; j < 4; ++j) {
        h2 pk;
        pk.x = (_Float16)p[(2 * j) * 256];
        pk.y = (_Float16)p[(2 * j + 1) * 256];
        r[j] = __builtin_bit_cast(unsigned, pk);
      }
      uint4 o;
      o.x = r[0]; o.y = r[1]; o.z = r[2]; o.w = r[3];
      wpk[PM_VU1 + pi] = o;
    }
  }

  if (blk < 128) {
    // ===== task path: 16 rows/block; TE2/FT frags prefetched early =====
    const int rb = blk * 16;
    const int bI = rb >> 8, t0 = rb & 255;
    _Float16* hT = (_Float16*)smem;  // [16][264]
    uint4 pfA[16];
    load_bfrags<2, 8>(wpk + FM_TE2, 2 * wq, 0, l, pfA);  // in flight early
    h8 a0;
    {
      const float* xr = task_obs + (size_t)(rb + l15) * 32 + 8 * l4;
      float4 xa = *(const float4*)xr;
      float4 xb = *(const float4*)(xr + 4);
      a0[0] = (_Float16)xa.x; a0[1] = (_Float16)xa.y;
      a0[2] = (_Float16)xa.z; a0[3] = (_Float16)xa.w;
      a0[4] = (_Float16)xb.x; a0[5] = (_Float16)xb.y;
      a0[6] = (_Float16)xb.z; a0[7] = (_Float16)xb.w;
    }
    f32x4 acc[2];
    mfma_gemm<2, 1, false>(wpk + FM_TE1, 2 * wq, 0, l, &a0, acc);
    epi_store<2, true>(acc, te_b1, wq * 32, wq * 32, l15, l4, hT, 264);
    __syncthreads();
    h8 afr[8];
    lda<8>(hT, l15, 264, l4, afr);
    __syncthreads();
    uint4 pfB[16];
    load_bfrags<2, 8>(wpk + FM_FT, 2 * wq, 0, l, pfB);  // hide under TE2
    mfma_from<2, 8, false>(pfA, afr, acc);  // TE2
    epi_store<2, false>(acc, te_b2, wq * 32, wq * 32, l15, l4, hT, 264);
    __syncthreads();
    lda<8>(hT, l15, 264, l4, afr);
    mfma_from<2, 8, false>(pfB, afr, acc);  // FT
#pragma unroll
    for (int nt = 0; nt < 2; ++nt) {
      float bv = ft_b[wq * 32 + nt * 16 + l15];
#pragma unroll
      for (int i = 0; i < 4; ++i) acc[nt][i] = fmaxf(acc[nt][i] + bv, 0.f);
    }
    ln_block8<true>(acc, ft_g, ft_bt, fn_g + 256, actor_w + 256,
                    valid_mask + bI * 256 + t0, stA, stB, wq, l, tid,
                    ws + WS_TPP + blk * 256, ws + WS_ST + rb, ws + WS_SUMT + rb,
                    ws + WS_SST + rb);
  } else if (blk < 160) {
    // ===== worker path: 16 rows/block; fully staged frag prefetch =====
    const int wbl = blk - 128;
    const int rbw = wbl * 16;
    _Float16* XW = (_Float16*)smem;             // [16][48]
    _Float16* h1 = (_Float16*)(smem + 1536);    // [16][264]
    _Float16* ct = (_Float16*)(smem + 9984);    // [16][528]
    uint4 pfA[16];
    load_bfrags<2, 8>(wpk + FM_WLE2, 2 * wq, 0, l, pfA);
    if (tid < 256) {
      int r = tid >> 4, k = tid & 15;
      XW[r * 48 + k] = (_Float16)worker_loads[(size_t)(rbw + r) * 16 + k];
      XW[r * 48 + 16 + k] = (_Float16)0.f;
    }
    __syncthreads();
    h8 ax = *(const h8*)(XW + l15 * 48 + 8 * l4);
    f32x4 acc[2];
    mfma_gemm<2, 1, false>(wpk + FM_WLE1, 2 * wq, 0, l, &ax, acc);
    epi_store<2, true>(acc, wle_b1, wq * 32, wq * 32, l15, l4, h1, 264);
    __syncthreads();
    h8 afr[8];
    lda<8>(h1, l15, 264, l4, afr);
    uint4 pfB[16];
    load_bfrags<2, 8>(wpk + FM_WPE2, 2 * wq, 0, l, pfB);
    uint4 pfS[2];
    load_bfrags<2, 1>(wpk + FM_WPE1, 2 * wq, 0, l, pfS);  // WPE1 prefetch
    for (int e = tid; e < 384; e += 512) {
      int r = e / 24, k = e - r * 24;
      XW[r * 48 + k] = (_Float16)worker_profiles[(size_t)(rbw + r) * 24 + k];
    }
    if (tid < 128) {
      int r = tid >> 3, k = 24 + (tid & 7);
      XW[r * 48 + k] = (_Float16)0.f;
    }
    __syncthreads();
    mfma_from<2, 8, false>(pfA, afr, acc);  // WLE2
    epi_store<2, false>(acc, wle_b2, wq * 32, wq * 32, l15, l4, ct, 528);
    ax = *(const h8*)(XW + l15 * 48 + 8 * l4);
    mfma_from<2, 1, false>(pfS, &ax, acc);  // WPE1 (prefetched)
    epi_store<2, true>(acc, wpe_b1, wq * 32, wq * 32, l15, l4, h1, 264);
    __syncthreads();
    lda<8>(h1, l15, 264, l4, afr);
    uint4 pfC[16];
    load_bfrags<2, 8>(wpk + FM_FW, 2 * wq, 0, l, pfC);  // FW ks 0..7
    mfma_from<2, 8, false>(pfB, afr, acc);  // WPE2
    epi_store<2, false>(acc, wpe_b2, wq * 32, 256 + wq * 32, l15, l4, ct, 528);
    uint4 pfD[16];
    load_bfrags<2, 8>(wpk + FM_FW, 2 * wq, 8, l, pfD);  // FW ks 8..15 early
    __syncthreads();
    h8 af2[16];
    lda<16>(ct, l15, 528, l4, af2);
    mfma_from<2, 8, false>(pfC, af2, acc);
    mfma_from<2, 8, true>(pfD, af2 + 8, acc);
#pragma unroll
    for (int nt = 0; nt < 2; ++nt) {
      float bv = fw_b[wq * 32 + nt * 16 + l15];
#pragma unroll
      for (int i = 0; i < 4; ++i) acc[nt][i] = fmaxf(acc[nt][i] + bv, 0.f);
    }
    ln_block8<false>(acc, fw_g, fw_bt, fn_g, actor_w, nullptr, stA, stB, wq, l,
                     tid, ws + WS_WPP + wbl * 256, ws + WS_SW + rbw,
                     ws + WS_SUMW + rbw, ws + WS_SSW + rbw);
  } else {
    // ===== global path: guarded 256-thread fdot2 (waves 4-7 idle) =====
    float* smf = (float*)smem;                  // 2056 floats
    unsigned* smp = (unsigned*)(smem + 8256);   // 1792 u32
    const int d = tid & 255;
    if (tid < 256)
      smp[tid] = pkrtz_u(global_context[2 * tid], global_context[2 * tid + 1]);
    __syncthreads();
    float acc[8], v[8];
    if (tid < 256) {
      gemmp<8, 8>(wpk + PM_G1, (const uint4*)smp, 8, d, acc);
      float b = g_b1[d];
#pragma unroll
      for (int r = 0; r < 8; ++r) v[r] = fmaxf(acc[r] + b, 0.f);
      shfl_pack<8>(v, smp + 256, 128, d);
    }
    __syncthreads();
    if (tid < 256) {
      gemmp<8, 32>(wpk + PM_G2, (const uint4*)(smp + 256), 32, d, acc);
      float b = g_b2[d];
#pragma unroll
      for (int r = 0; r < 8; ++r) {
        float x = acc[r] + b;
        ws[WS_GFEAT + r * D_ + d] = x;
        smf[r * D_ + d] = x;
      }
      float c0 = 0.f, c1 = 0.f;
      for (int i = tid; i < 768; i += 256) {
        float aw = actor_w[i];
        c0 = fmaf(fn_b[i], aw, c0);
        c1 = fmaf(fn_g[i], aw, c1);
      }
      c0 = wave_sum(c0);
      c1 = wave_sum(c1);
      const int wv = tid >> 6, lane = tid & 63;
      if (lane == 0) {
        smf[2048 + wv] = c0;
        smf[2052 + wv] = c1;
      }
    }
    __syncthreads();
    if (tid < 256) {
      const int wv = tid >> 6, lane = tid & 63;
      for (int r = wv; r < 8; r += 4) {
        float a1 = 0.f, a2 = 0.f, a3 = 0.f;
        for (int j = lane; j < D_; j += 64) {
          float x = smf[r * D_ + j];
          a1 = fmaf(x, fn_g[512 + j] * actor_w[512 + j], a1);
          a2 += x;
          a3 = fmaf(x, x, a3);
        }
        a1 = wave_sum(a1);
        a2 = wave_sum(a2);
        a3 = wave_sum(a3);
        if (lane == 0) {
          ws[WS_SG + r] = a1;
          ws[WS_SUMG + r] = a2;
          ws[WS_SSG + r] = a3;
        }
      }
      if (tid == 0) {
        ws[WS_C0] = smf[2048] + smf[2049] + smf[2050] + smf[2051] + actor_b[0];
        ws[WS_C1] = smf[2052] + smf[2053] + smf[2054] + smf[2055];
      }
    }
  }
}

// -------------------- heads: 272 blocks x 512 threads --------------------
__global__ __launch_bounds__(512) void head_kernel(
    const float* __restrict__ valid_mask, const float* __restrict__ log_std,
    const float* __restrict__ vu_b1, const float* __restrict__ vu_b2,
    const float* __restrict__ vc_b1, const float* __restrict__ vc_b2,
    const float* __restrict__ vu_w2, const float* __restrict__ vc_w2,
    const uint4* __restrict__ wpk, const float* __restrict__ ws,
    float* __restrict__ out) {
  const int tid = threadIdx.x;
  const int blk = blockIdx.x;
  if (blk < 16) {
    // value heads: block = (head, b); K=768 split across thread halves
    const int head = blk >> 3;
    const int b = blk & 7;
    __shared__ float lm[256];
    __shared__ float red[8];
    __shared__ __align__(16) unsigned vcip[384];
    __shared__ float hl[512];
    if (tid < 256) lm[tid] = valid_mask[b * T_ + tid];
    __syncthreads();
    if (tid < 256) {
      float m = wave_sum(lm[tid]);
      if ((tid & 63) == 0) red[tid >> 6] = m;
    }
    __syncthreads();
    const float mdiv = 1.f / fmaxf(red[0] + red[1] + red[2] + red[3], 1.f);
    if (tid < 256) {
      float vv[3];
      float acc = 0.f;
#pragma unroll
      for (int c = 0; c < 16; ++c)
        acc += ws[WS_TPP + (b * 16 + c) * 256 + tid];
      vv[0] = acc * mdiv;
      acc = 0.f;
#pragma unroll
      for (int c = 0; c < 4; ++c) acc += ws[WS_WPP + (b * 4 + c) * 256 + tid];
      vv[1] = acc * (1.f / 64.f);
      vv[2] = ws[WS_GFEAT + b * D_ + tid];
      shfl_pack<3>(vv, vcip, 128, tid);
    }
    __syncthreads();
    const uint4* w1p = wpk + (head ? PM_VC1 : PM_VU1);
    const float* b1 = head ? vc_b1 : vu_b1;
    const float* w2 = head ? vc_w2 : vu_w2;
    const float* b2 = head ? vc_b2 : vu_b2;
    const uint4* xq = (const uint4*)vcip;
    const int col = tid & 255, kh = tid >> 8;
    float h = 0.f;
#pragma unroll 8
    for (int g = 48 * kh; g < 48 * kh + 48; ++g) {
      uint4 w = w1p[g * 256 + col];
      uint4 x = xq[g];
      h = fdot2u(x.x, w.x, h);
      h = fdot2u(x.y, w.y, h);
      h = fdot2u(x.z, w.z, h);
      h = fdot2u(x.w, w.w, h);
    }
    hl[tid] = h;
    __syncthreads();
    if (tid < 256) {
      float hv = fmaxf(hl[tid] + hl[256 + tid] + b1[tid], 0.f);
      float c = wave_sum(hv * w2[tid]);
      if ((tid & 63) == 0) red[tid >> 6] = c;
    }
    __syncthreads();
    if (tid == 0)
      out[2 * B_ * W_ * T_ + head * B_ + b] =
          red[0] + red[1] + red[2] + red[3] + b2[0];
  } else {
    // actor: blocks 16..271, 1 elem/thread (256 x 512 = 131072 exactly)
    const int idx = (blk - 16) * 512 + tid;
    const float C0 = ws[WS_C0];
    const float C1 = ws[WS_C1];
    const int b = idx >> 14;
    const int w = (idx >> 8) & 63;
    const int t = idx & 255;
    float S = ws[WS_SW + b * W_ + w] + ws[WS_ST + b * T_ + t] + ws[WS_SG + b];
    float sum =
        ws[WS_SUMW + b * W_ + w] + ws[WS_SUMT + b * T_ + t] + ws[WS_SUMG + b];
    float ssq =
        ws[WS_SSW + b * W_ + w] + ws[WS_SST + b * T_ + t] + ws[WS_SSG + b];
    float mu = sum * (1.f / 768.f);
    float var = ssq * (1.f / 768.f) - mu * mu;
    float inv = rsqrtf(var + 1e-5f);
    float logit = inv * (S - mu * C1) + C0;
    out[idx] = 1.f / (1.f + expf(-logit));
    float ls = log_std[w * T_ + t];
    out[B_ * W_ * T_ + idx] = expf(fminf(fmaxf(ls, -4.f), 1.f));
  }
}

}  // namespace

extern "C" void kernel_launch(void* const* d_in, const int* in_sizes, int n_in,
                              void* d_out, int out_size, void* d_ws,
                              size_t ws_size, hipStream_t stream) {
  (void)in_sizes; (void)n_in; (void)out_size; (void)ws_size;
  const float* task_obs        = (const float*)d_in[0];
  const float* worker_loads    = (const float*)d_in[1];
  const float* worker_profiles = (const float*)d_in[2];
  const float* global_context  = (const float*)d_in[3];
  const float* valid_mask      = (const float*)d_in[4];
  const float* te_w1  = (const float*)d_in[5];
  const float* te_b1  = (const float*)d_in[6];
  const float* te_w2  = (const float*)d_in[7];
  const float* te_b2  = (const float*)d_in[8];
  const float* wle_w1 = (const float*)d_in[9];
  const float* wle_b1 = (const float*)d_in[10];
  const float* wle_w2 = (const float*)d_in[11];
  const float* wle_b2 = (const float*)d_in[12];
  const float* wpe_w1 = (const float*)d_in[13];
  const float* wpe_b1 = (const float*)d_in[14];
  const float* wpe_w2 = (const float*)d_in[15];
  const float* wpe_b2 = (const float*)d_in[16];
  const float* ft_w   = (const float*)d_in[17];
  const float* ft_b   = (const float*)d_in[18];
  const float* ft_g   = (const float*)d_in[19];
  const float* ft_bt  = (const float*)d_in[20];
  const float* fw_w   = (const float*)d_in[21];
  const float* fw_b   = (const float*)d_in[22];
  const float* fw_g   = (const float*)d_in[23];
  const float* fw_bt  = (const float*)d_in[24];
  const float* g_w1   = (const float*)d_in[25];
  const float* g_b1   = (const float*)d_in[26];
  const float* g_w2   = (const float*)d_in[27];
  const float* g_b2   = (const float*)d_in[28];
  const float* fn_g   = (const float*)d_in[29];
  const float* fn_b   = (const float*)d_in[30];
  const float* actor_w = (const float*)d_in[31];
  const float* actor_b = (const float*)d_in[32];
  const float* log_std = (const float*)d_in[33];
  const float* vu_w1  = (const float*)d_in[34];
  const float* vu_b1  = (const float*)d_in[35];
  const float* vu_w2  = (const float*)d_in[36];
  const float* vu_b2  = (const float*)d_in[37];
  const float* vc_w1  = (const float*)d_in[38];
  const float* vc_b1  = (const float*)d_in[39];
  const float* vc_w2  = (const float*)d_in[40];
  const float* vc_b2  = (const float*)d_in[41];
  float* ws = (float*)d_ws;
  uint4* wpk = (uint4*)(ws + WS_PK);
  float* out = (float*)d_out;

  hipLaunchKernelGGL(pack_kernel, dim3(PK_ENC / 256), dim3(256), 0, stream,
                     te_w1, te_w2, ft_w, wle_w1, wle_w2, wpe_w1, wpe_w2, fw_w,
                     g_w1, g_w2, wpk);
  hipLaunchKernelGGL(enc_kernel, dim3(161), dim3(512), 0, stream, task_obs,
                     worker_loads, worker_profiles, global_context, valid_mask,
                     vu_w1, vc_w1, te_b1, te_b2, wle_b1, wle_b2, wpe_b1,
                     wpe_b2, ft_b, ft_g, ft_bt, fw_b, fw_g, fw_bt, g_b1, g_b2,
                     fn_g, fn_b, actor_w, actor_b, ws);
  hipLaunchKernelGGL(head_kernel, dim3(272), dim3(512), 0, stream, valid_mask,
                     log_std, vu_b1, vu_b2, vc_b1, vc_b2, vu_w2, vc_w2,
                     (const uint4*)wpk, (const float*)ws, out);
}

// Round 19
// 28.923 us; speedup vs baseline: 1.0049x; 1.0049x over previous
//
#include <hip/hip_runtime.h>
#include <math.h>

namespace {

constexpr int B_ = 8, W_ = 64, T_ = 256, D_ = 256;

typedef _Float16 h2 __attribute__((ext_vector_type(2)));
typedef _Float16 h8 __attribute__((ext_vector_type(8)));
typedef float f32x4 __attribute__((ext_vector_type(4)));
typedef __fp16 fp16v2 __attribute__((ext_vector_type(2)));

// -------- workspace layout (float offsets) --------
constexpr int WS_ST    = 0;       // B*T
constexpr int WS_SUMT  = 2048;
constexpr int WS_SST   = 4096;
constexpr int WS_SW    = 6144;    // B*W
constexpr int WS_SUMW  = 6656;
constexpr int WS_SSW   = 7168;
constexpr int WS_SG    = 7680;    // B
constexpr int WS_SUMG  = 7688;
constexpr int WS_SSG   = 7696;
constexpr int WS_C0    = 7704;
constexpr int WS_C1    = 7705;
constexpr int WS_GFEAT = 7712;    // B*D
constexpr int WS_TPP   = 9760;    // 128 * 256
constexpr int WS_WPP   = 42528;   // 32 * 256
constexpr int WS_PK    = 665120;  // packed weights (16B-aligned)

// ---- packed-weight offsets (uint4 units) ----
constexpr int FM_TE1  = 0;
constexpr int FM_TE2  = 1024;
constexpr int FM_FT   = 9216;
constexpr int FM_WLE1 = 17408;
constexpr int FM_WLE2 = 18432;
constexpr int FM_WPE1 = 26624;
constexpr int FM_WPE2 = 27648;
constexpr int FM_FW   = 35840;
constexpr int FM_END  = 52224;
constexpr int PM_G1   = 52224;
constexpr int PM_G2   = 54272;
constexpr int PM_VU1  = 62464;
constexpr int PM_VC1  = 87040;
constexpr int PK_TOTAL = 111616;  // /256 = 436 blocks

__device__ __forceinline__ float wave_sum(float v) {
#pragma unroll
  for (int m = 32; m > 0; m >>= 1) v += __shfl_xor(v, m, 64);
  return v;
}

__device__ __forceinline__ float red16(float v) {
  v += __shfl_xor(v, 1, 64);
  v += __shfl_xor(v, 2, 64);
  v += __shfl_xor(v, 4, 64);
  v += __shfl_xor(v, 8, 64);
  return v;
}

__device__ __forceinline__ unsigned pkrtz_u(float a, float b) {
  fp16v2 p = __builtin_amdgcn_cvt_pkrtz(a, b);
  return __builtin_bit_cast(unsigned, p);
}

__device__ __forceinline__ float fdot2u(unsigned x, unsigned w, float c) {
#if __has_builtin(__builtin_amdgcn_fdot2)
  return __builtin_amdgcn_fdot2(__builtin_bit_cast(h2, x),
                                __builtin_bit_cast(h2, w), c, false);
#else
  h2 a = __builtin_bit_cast(h2, x);
  h2 b = __builtin_bit_cast(h2, w);
  float r = fmaf((float)a.x, (float)b.x, c);
  return fmaf((float)a.y, (float)b.y, r);
#endif
}

template <int R, int G>
__device__ __forceinline__ void gemmp(const uint4* __restrict__ Wp,
                                      const uint4* xp, int xs, int d,
                                      float* acc) {
#pragma unroll
  for (int r = 0; r < R; ++r) acc[r] = 0.f;
#pragma unroll 4
  for (int g = 0; g < G; ++g) {
    uint4 w = Wp[g * 256 + d];
#pragma unroll
    for (int r = 0; r < R; ++r) {
      uint4 x = xp[r * xs + g];
      acc[r] = fdot2u(x.x, w.x, acc[r]);
      acc[r] = fdot2u(x.y, w.y, acc[r]);
      acc[r] = fdot2u(x.z, w.z, acc[r]);
      acc[r] = fdot2u(x.w, w.w, acc[r]);
    }
  }
}

template <int R>
__device__ __forceinline__ void shfl_pack(const float* v, unsigned* dst,
                                          int stride, int d) {
#pragma unroll
  for (int r = 0; r < R; ++r) {
    float p = __shfl_xor(v[r], 1, 64);
    unsigned pk = (d & 1) ? pkrtz_u(p, v[r]) : pkrtz_u(v[r], p);
    if (!(d & 1)) dst[r * stride + (d >> 1)] = pk;
  }
}

// ---- cross-stage B-fragment prefetch (validated R9/R15) ----
template <int NT, int KS>
__device__ __forceinline__ void load_bfrags(const uint4* __restrict__ wb,
                                            int nt0, int ks0, int l,
                                            uint4* pf) {
#pragma unroll
  for (int nt = 0; nt < NT; ++nt)
#pragma unroll
    for (int ks = 0; ks < KS; ++ks)
      pf[nt * KS + ks] = wb[((ks0 + ks) * 16 + nt0 + nt) * 64 + l];
}

template <int NT, int KS, bool ACC_IN>
__device__ __forceinline__ void mfma_from(const uint4* pf, const h8* afr,
                                          f32x4* acc) {
#pragma unroll
  for (int nt = 0; nt < NT; ++nt) {
    f32x4 c;
    if (ACC_IN) c = acc[nt];
    else { c[0] = 0.f; c[1] = 0.f; c[2] = 0.f; c[3] = 0.f; }
#pragma unroll
    for (int ks = 0; ks < KS; ++ks)
      c = __builtin_amdgcn_mfma_f32_16x16x32_f16(
          afr[ks], __builtin_bit_cast(h8, pf[nt * KS + ks]), c, 0, 0, 0);
    acc[nt] = c;
  }
}

template <int NT, int KS, bool ACC_IN>
__device__ __forceinline__ void mfma_gemm(const uint4* __restrict__ wb,
                                          int nt0, int ks0, int l,
                                          const h8* afr, f32x4* acc) {
  uint4 pf[NT * KS];
  load_bfrags<NT, KS>(wb, nt0, ks0, l, pf);
  mfma_from<NT, KS, ACC_IN>(pf, afr, acc);
}

template <int KS>
__device__ __forceinline__ void lda(const _Float16* src, int row, int stride,
                                    int l4, h8* afr) {
#pragma unroll
  for (int ks = 0; ks < KS; ++ks)
    afr[ks] = *(const h8*)(src + row * stride + ks * 32 + 8 * l4);
}

template <int NT, bool RELU>
__device__ __forceinline__ void epi_store(const f32x4* acc,
                                          const float* __restrict__ bias,
                                          int c0, int dc0, int l15, int l4,
                                          _Float16* dst, int stride) {
#pragma unroll
  for (int nt = 0; nt < NT; ++nt) {
    float bv = bias[c0 + nt * 16 + l15];
    int dc = dc0 + nt * 16 + l15;
#pragma unroll
    for (int i = 0; i < 4; ++i) {
      float v = acc[nt][i] + bv;
      if (RELU) v = fmaxf(v, 0.f);
      dst[(l4 * 4 + i) * stride + dc] = (_Float16)v;
    }
  }
}

// Full-row LN across 8 waves x 2 nt; wave owns cols 32*wq.
template <bool MASKED>
__device__ __forceinline__ void ln_block8(
    f32x4* acc, const float* __restrict__ g, const float* __restrict__ bt,
    const float* __restrict__ fn_g_seg, const float* __restrict__ aw_seg,
    const float* __restrict__ mask_base, float* stA, float* stB, int wq, int l,
    int tid, float* __restrict__ pool, float* __restrict__ Sd,
    float* __restrict__ sumd, float* __restrict__ ssd) {
  const int l15 = l & 15, l4 = l >> 4;
#pragma unroll
  for (int i = 0; i < 4; ++i) {
    float s = 0.f, ss = 0.f;
#pragma unroll
    for (int nt = 0; nt < 2; ++nt) {
      float v = acc[nt][i];
      s += v;
      ss = fmaf(v, v, ss);
    }
    s = red16(s);
    ss = red16(ss);
    if (l15 == 0) {
      int row = l4 * 4 + i;
      stA[(row * 8 + wq) * 2 + 0] = s;
      stA[(row * 8 + wq) * 2 + 1] = ss;
    }
  }
  __syncthreads();
  float gg[2], bb[2], fa[2];
#pragma unroll
  for (int nt = 0; nt < 2; ++nt) {
    int c = wq * 32 + nt * 16 + l15;
    gg[nt] = g[c];
    bb[nt] = bt[c];
    fa[nt] = fn_g_seg[c] * aw_seg[c];
  }
  float pp[2] = {0.f, 0.f};
#pragma unroll
  for (int i = 0; i < 4; ++i) {
    int row = l4 * 4 + i;
    float s = 0.f, ss = 0.f;
#pragma unroll
    for (int q = 0; q < 8; ++q) {
      s += stA[(row * 8 + q) * 2];
      ss += stA[(row * 8 + q) * 2 + 1];
    }
    float mu = s * (1.f / 256.f);
    float var = ss * (1.f / 256.f) - mu * mu;
    float inv = rsqrtf(var + 1e-5f);
    float mk = MASKED ? mask_base[row] : 1.f;
    float a1 = 0.f, a2 = 0.f, a3 = 0.f;
#pragma unroll
    for (int nt = 0; nt < 2; ++nt) {
      float v = (acc[nt][i] - mu) * inv * gg[nt] + bb[nt];
      a1 = fmaf(v, fa[nt], a1);
      a2 += v;
      a3 = fmaf(v, v, a3);
      pp[nt] = fmaf(mk, v, pp[nt]);
    }
    a1 = red16(a1);
    a2 = red16(a2);
    a3 = red16(a3);
    if (l15 == 0) {
      stB[(row * 8 + wq) * 3 + 0] = a1;
      stB[(row * 8 + wq) * 3 + 1] = a2;
      stB[(row * 8 + wq) * 3 + 2] = a3;
    }
  }
#pragma unroll
  for (int nt = 0; nt < 2; ++nt) {
    pp[nt] += __shfl_xor(pp[nt], 16, 64);
    pp[nt] += __shfl_xor(pp[nt], 32, 64);
  }
  if (l < 16) {
#pragma unroll
    for (int nt = 0; nt < 2; ++nt) pool[wq * 32 + nt * 16 + l15] = pp[nt];
  }
  __syncthreads();
  if (tid < 16) {
    int row = tid;
    float sA = 0.f, sB = 0.f, sC = 0.f;
#pragma unroll
    for (int q = 0; q < 8; ++q) {
      sA += stB[(row * 8 + q) * 3 + 0];
      sB += stB[(row * 8 + q) * 3 + 1];
      sC += stB[(row * 8 + q) * 3 + 2];
    }
    Sd[row] = sA;
    sumd[row] = sB;
    ssd[row] = sC;
  }
}

// -------------------- weight pre-pack --------------------
__global__ __launch_bounds__(256) void pack_kernel(
    const float* __restrict__ te_w1, const float* __restrict__ te_w2,
    const float* __restrict__ ft_w, const float* __restrict__ wle_w1,
    const float* __restrict__ wle_w2, const float* __restrict__ wpe_w1,
    const float* __restrict__ wpe_w2, const float* __restrict__ fw_w,
    const float* __restrict__ g_w1, const float* __restrict__ g_w2,
    const float* __restrict__ vu_w1, const float* __restrict__ vc_w1,
    uint4* __restrict__ dst) {
  int i = blockIdx.x * 256 + threadIdx.x;
  if (i < FM_END) {
    const float* src; int off, Ksrc;
    if      (i < FM_TE2)  { src = te_w1;  off = FM_TE1;  Ksrc = 32;  }
    else if (i < FM_FT)   { src = te_w2;  off = FM_TE2;  Ksrc = 256; }
    else if (i < FM_WLE1) { src = ft_w;   off = FM_FT;   Ksrc = 256; }
    else if (i < FM_WLE2) { src = wle_w1; off = FM_WLE1; Ksrc = 16;  }
    else if (i < FM_WPE1) { src = wle_w2; off = FM_WLE2; Ksrc = 256; }
    else if (i < FM_WPE2) { src = wpe_w1; off = FM_WPE1; Ksrc = 24;  }
    else if (i < FM_FW)   { src = wpe_w2; off = FM_WPE2; Ksrc = 256; }
    else                  { src = fw_w;   off = FM_FW;   Ksrc = 512; }
    int li = i - off;
    int l = li & 63, nt = (li >> 6) & 15, ks = li >> 10;
    int n = nt * 16 + (l & 15);
    int k0 = ks * 32 + 8 * (l >> 4);
    h8 v;
#pragma unroll
    for (int j = 0; j < 8; ++j) {
      int k = k0 + j;
      v[j] = (k < Ksrc) ? (_Float16)src[(size_t)k * 256 + n] : (_Float16)0.f;
    }
    dst[i] = __builtin_bit_cast(uint4, v);
  } else {
    const float* src; int off;
    if      (i < PM_G2)  { src = g_w1;  off = PM_G1;  }
    else if (i < PM_VU1) { src = g_w2;  off = PM_G2;  }
    else if (i < PM_VC1) { src = vu_w1; off = PM_VU1; }
    else                 { src = vc_w1; off = PM_VC1; }
    int li = i - off;
    int g = li >> 8, d = li & 255;
    const float* p = src + (size_t)g * 8 * 256 + d;
    unsigned r[4];
#pragma unroll
    for (int j = 0; j < 4; ++j) {
      h2 pk;
      pk.x = (_Float16)p[(2 * j) * 256];
      pk.y = (_Float16)p[(2 * j + 1) * 256];
      r[j] = __builtin_bit_cast(unsigned, pk);
    }
    uint4 o;
    o.x = r[0]; o.y = r[1]; o.z = r[2]; o.w = r[3];
    dst[i] = o;
  }
}

// -------------------- fused encoders: 161 blocks x 512 threads --------------
__global__ __launch_bounds__(512) void enc_kernel(
    const float* __restrict__ task_obs, const float* __restrict__ worker_loads,
    const float* __restrict__ worker_profiles,
    const float* __restrict__ global_context,
    const float* __restrict__ valid_mask, const float* __restrict__ te_b1,
    const float* __restrict__ te_b2, const float* __restrict__ wle_b1,
    const float* __restrict__ wle_b2, const float* __restrict__ wpe_b1,
    const float* __restrict__ wpe_b2, const float* __restrict__ ft_b,
    const float* __restrict__ ft_g, const float* __restrict__ ft_bt,
    const float* __restrict__ fw_b, const float* __restrict__ fw_g,
    const float* __restrict__ fw_bt, const float* __restrict__ g_b1,
    const float* __restrict__ g_b2, const float* __restrict__ fn_g,
    const float* __restrict__ fn_b, const float* __restrict__ actor_w,
    const float* __restrict__ actor_b, const uint4* __restrict__ wpk,
    float* __restrict__ ws) {
  __shared__ __align__(16) unsigned char smem[29440];
  const int tid = threadIdx.x;
  const int blk = blockIdx.x;
  const int w = tid >> 6, l = tid & 63;
  const int l15 = l & 15, l4 = l >> 4;
  // De-lockstep rotation (R10, validated): wave w owns column-tile wq.
  const int swz = ((blk >> 3) + blk) & 7;
  const int wq = (w + swz) & 7;
  float* stA = (float*)(smem + 26880);  // 256 floats
  float* stB = (float*)(smem + 27904);  // 384 floats

  if (blk < 128) {
    // ===== task path: 16 rows/block; TE2/FT frags prefetched early =====
    const int rb = blk * 16;
    const int bI = rb >> 8, t0 = rb & 255;
    _Float16* hT = (_Float16*)smem;  // [16][264]
    uint4 pfA[16];
    load_bfrags<2, 8>(wpk + FM_TE2, 2 * wq, 0, l, pfA);  // in flight early
    h8 a0;
    {
      const float* xr = task_obs + (size_t)(rb + l15) * 32 + 8 * l4;
      float4 xa = *(const float4*)xr;
      float4 xb = *(const float4*)(xr + 4);
      a0[0] = (_Float16)xa.x; a0[1] = (_Float16)xa.y;
      a0[2] = (_Float16)xa.z; a0[3] = (_Float16)xa.w;
      a0[4] = (_Float16)xb.x; a0[5] = (_Float16)xb.y;
      a0[6] = (_Float16)xb.z; a0[7] = (_Float16)xb.w;
    }
    f32x4 acc[2];
    mfma_gemm<2, 1, false>(wpk + FM_TE1, 2 * wq, 0, l, &a0, acc);
    epi_store<2, true>(acc, te_b1, wq * 32, wq * 32, l15, l4, hT, 264);
    __syncthreads();
    h8 afr[8];
    lda<8>(hT, l15, 264, l4, afr);
    __syncthreads();
    uint4 pfB[16];
    load_bfrags<2, 8>(wpk + FM_FT, 2 * wq, 0, l, pfB);  // hide under TE2
    mfma_from<2, 8, false>(pfA, afr, acc);  // TE2
    epi_store<2, false>(acc, te_b2, wq * 32, wq * 32, l15, l4, hT, 264);
    __syncthreads();
    lda<8>(hT, l15, 264, l4, afr);
    mfma_from<2, 8, false>(pfB, afr, acc);  // FT
#pragma unroll
    for (int nt = 0; nt < 2; ++nt) {
      float bv = ft_b[wq * 32 + nt * 16 + l15];
#pragma unroll
      for (int i = 0; i < 4; ++i) acc[nt][i] = fmaxf(acc[nt][i] + bv, 0.f);
    }
    ln_block8<true>(acc, ft_g, ft_bt, fn_g + 256, actor_w + 256,
                    valid_mask + bI * 256 + t0, stA, stB, wq, l, tid,
                    ws + WS_TPP + blk * 256, ws + WS_ST + rb, ws + WS_SUMT + rb,
                    ws + WS_SST + rb);
  } else if (blk < 160) {
    // ===== worker path: 16 rows/block; fully staged frag prefetch =====
    const int wbl = blk - 128;
    const int rbw = wbl * 16;
    _Float16* XW = (_Float16*)smem;             // [16][48]
    _Float16* h1 = (_Float16*)(smem + 1536);    // [16][264]
    _Float16* ct = (_Float16*)(smem + 9984);    // [16][528]
    uint4 pfA[16];
    load_bfrags<2, 8>(wpk + FM_WLE2, 2 * wq, 0, l, pfA);
    if (tid < 256) {
      int r = tid >> 4, k = tid & 15;
      XW[r * 48 + k] = (_Float16)worker_loads[(size_t)(rbw + r) * 16 + k];
      XW[r * 48 + 16 + k] = (_Float16)0.f;
    }
    __syncthreads();
    h8 ax = *(const h8*)(XW + l15 * 48 + 8 * l4);
    f32x4 acc[2];
    mfma_gemm<2, 1, false>(wpk + FM_WLE1, 2 * wq, 0, l, &ax, acc);
    epi_store<2, true>(acc, wle_b1, wq * 32, wq * 32, l15, l4, h1, 264);
    __syncthreads();
    h8 afr[8];
    lda<8>(h1, l15, 264, l4, afr);
    uint4 pfB[16];
    load_bfrags<2, 8>(wpk + FM_WPE2, 2 * wq, 0, l, pfB);
    uint4 pfS[2];
    load_bfrags<2, 1>(wpk + FM_WPE1, 2 * wq, 0, l, pfS);  // WPE1 prefetch
    for (int e = tid; e < 384; e += 512) {
      int r = e / 24, k = e - r * 24;
      XW[r * 48 + k] = (_Float16)worker_profiles[(size_t)(rbw + r) * 24 + k];
    }
    if (tid < 128) {
      int r = tid >> 3, k = 24 + (tid & 7);
      XW[r * 48 + k] = (_Float16)0.f;
    }
    __syncthreads();
    mfma_from<2, 8, false>(pfA, afr, acc);  // WLE2
    epi_store<2, false>(acc, wle_b2, wq * 32, wq * 32, l15, l4, ct, 528);
    ax = *(const h8*)(XW + l15 * 48 + 8 * l4);
    mfma_from<2, 1, false>(pfS, &ax, acc);  // WPE1 (prefetched)
    epi_store<2, true>(acc, wpe_b1, wq * 32, wq * 32, l15, l4, h1, 264);
    __syncthreads();
    lda<8>(h1, l15, 264, l4, afr);
    uint4 pfC[16];
    load_bfrags<2, 8>(wpk + FM_FW, 2 * wq, 0, l, pfC);  // FW ks 0..7
    mfma_from<2, 8, false>(pfB, afr, acc);  // WPE2
    epi_store<2, false>(acc, wpe_b2, wq * 32, 256 + wq * 32, l15, l4, ct, 528);
    uint4 pfD[16];
    load_bfrags<2, 8>(wpk + FM_FW, 2 * wq, 8, l, pfD);  // FW ks 8..15 early
    __syncthreads();
    h8 af2[16];
    lda<16>(ct, l15, 528, l4, af2);
    mfma_from<2, 8, false>(pfC, af2, acc);
    mfma_from<2, 8, true>(pfD, af2 + 8, acc);
#pragma unroll
    for (int nt = 0; nt < 2; ++nt) {
      float bv = fw_b[wq * 32 + nt * 16 + l15];
#pragma unroll
      for (int i = 0; i < 4; ++i) acc[nt][i] = fmaxf(acc[nt][i] + bv, 0.f);
    }
    ln_block8<false>(acc, fw_g, fw_bt, fn_g, actor_w, nullptr, stA, stB, wq, l,
                     tid, ws + WS_WPP + wbl * 256, ws + WS_SW + rbw,
                     ws + WS_SUMW + rbw, ws + WS_SSW + rbw);
  } else {
    // ===== global path: guarded 256-thread fdot2 (waves 4-7 idle) =====
    float* smf = (float*)smem;                  // 2056 floats
    unsigned* smp = (unsigned*)(smem + 8256);   // 1792 u32
    const int d = tid & 255;
    if (tid < 256)
      smp[tid] = pkrtz_u(global_context[2 * tid], global_context[2 * tid + 1]);
    __syncthreads();
    float acc[8], v[8];
    if (tid < 256) {
      gemmp<8, 8>(wpk + PM_G1, (const uint4*)smp, 8, d, acc);
      float b = g_b1[d];
#pragma unroll
      for (int r = 0; r < 8; ++r) v[r] = fmaxf(acc[r] + b, 0.f);
      shfl_pack<8>(v, smp + 256, 128, d);
    }
    __syncthreads();
    if (tid < 256) {
      gemmp<8, 32>(wpk + PM_G2, (const uint4*)(smp + 256), 32, d, acc);
      float b = g_b2[d];
#pragma unroll
      for (int r = 0; r < 8; ++r) {
        float x = acc[r] + b;
        ws[WS_GFEAT + r * D_ + d] = x;
        smf[r * D_ + d] = x;
      }
      float c0 = 0.f, c1 = 0.f;
      for (int i = tid; i < 768; i += 256) {
        float aw = actor_w[i];
        c0 = fmaf(fn_b[i], aw, c0);
        c1 = fmaf(fn_g[i], aw, c1);
      }
      c0 = wave_sum(c0);
      c1 = wave_sum(c1);
      const int wv = tid >> 6, lane = tid & 63;
      if (lane == 0) {
        smf[2048 + wv] = c0;
        smf[2052 + wv] = c1;
      }
    }
    __syncthreads();
    if (tid < 256) {
      const int wv = tid >> 6, lane = tid & 63;
      for (int r = wv; r < 8; r += 4) {
        float a1 = 0.f, a2 = 0.f, a3 = 0.f;
        for (int j = lane; j < D_; j += 64) {
          float x = smf[r * D_ + j];
          a1 = fmaf(x, fn_g[512 + j] * actor_w[512 + j], a1);
          a2 += x;
          a3 = fmaf(x, x, a3);
        }
        a1 = wave_sum(a1);
        a2 = wave_sum(a2);
        a3 = wave_sum(a3);
        if (lane == 0) {
          ws[WS_SG + r] = a1;
          ws[WS_SUMG + r] = a2;
          ws[WS_SSG + r] = a3;
        }
      }
      if (tid == 0) {
        ws[WS_C0] = smf[2048] + smf[2049] + smf[2050] + smf[2051] + actor_b[0];
        ws[WS_C1] = smf[2052] + smf[2053] + smf[2054] + smf[2055];
      }
    }
  }
}

// -------------------- heads: 272 blocks x 512 threads --------------------
__global__ __launch_bounds__(512) void head_kernel(
    const float* __restrict__ valid_mask, const float* __restrict__ log_std,
    const float* __restrict__ vu_b1, const float* __restrict__ vu_b2,
    const float* __restrict__ vc_b1, const float* __restrict__ vc_b2,
    const float* __restrict__ vu_w2, const float* __restrict__ vc_w2,
    const uint4* __restrict__ wpk, const float* __restrict__ ws,
    float* __restrict__ out) {
  const int tid = threadIdx.x;
  const int blk = blockIdx.x;
  if (blk < 16) {
    // value heads: block = (head, b); K=768 split across thread halves
    const int head = blk >> 3;
    const int b = blk & 7;
    __shared__ float lm[256];
    __shared__ float red[8];
    __shared__ __align__(16) unsigned vcip[384];
    __shared__ float hl[512];
    if (tid < 256) lm[tid] = valid_mask[b * T_ + tid];
    __syncthreads();
    if (tid < 256) {
      float m = wave_sum(lm[tid]);
      if ((tid & 63) == 0) red[tid >> 6] = m;
    }
    __syncthreads();
    const float mdiv = 1.f / fmaxf(red[0] + red[1] + red[2] + red[3], 1.f);
    if (tid < 256) {
      float vv[3];
      float acc = 0.f;
#pragma unroll
      for (int c = 0; c < 16; ++c)
        acc += ws[WS_TPP + (b * 16 + c) * 256 + tid];
      vv[0] = acc * mdiv;
      acc = 0.f;
#pragma unroll
      for (int c = 0; c < 4; ++c) acc += ws[WS_WPP + (b * 4 + c) * 256 + tid];
      vv[1] = acc * (1.f / 64.f);
      vv[2] = ws[WS_GFEAT + b * D_ + tid];
      shfl_pack<3>(vv, vcip, 128, tid);
    }
    __syncthreads();
    const uint4* w1p = wpk + (head ? PM_VC1 : PM_VU1);
    const float* b1 = head ? vc_b1 : vu_b1;
    const float* w2 = head ? vc_w2 : vu_w2;
    const float* b2 = head ? vc_b2 : vu_b2;
    const uint4* xq = (const uint4*)vcip;
    const int col = tid & 255, kh = tid >> 8;
    float h = 0.f;
#pragma unroll 8
    for (int g = 48 * kh; g < 48 * kh + 48; ++g) {
      uint4 w = w1p[g * 256 + col];
      uint4 x = xq[g];
      h = fdot2u(x.x, w.x, h);
      h = fdot2u(x.y, w.y, h);
      h = fdot2u(x.z, w.z, h);
      h = fdot2u(x.w, w.w, h);
    }
    hl[tid] = h;
    __syncthreads();
    if (tid < 256) {
      float hv = fmaxf(hl[tid] + hl[256 + tid] + b1[tid], 0.f);
      float c = wave_sum(hv * w2[tid]);
      if ((tid & 63) == 0) red[tid >> 6] = c;
    }
    __syncthreads();
    if (tid == 0)
      out[2 * B_ * W_ * T_ + head * B_ + b] =
          red[0] + red[1] + red[2] + red[3] + b2[0];
  } else {
    // actor: blocks 16..271, 1 elem/thread (256 x 512 = 131072 exactly)
    const int idx = (blk - 16) * 512 + tid;
    const float C0 = ws[WS_C0];
    const float C1 = ws[WS_C1];
    const int b = idx >> 14;
    const int w = (idx >> 8) & 63;
    const int t = idx & 255;
    float S = ws[WS_SW + b * W_ + w] + ws[WS_ST + b * T_ + t] + ws[WS_SG + b];
    float sum =
        ws[WS_SUMW + b * W_ + w] + ws[WS_SUMT + b * T_ + t] + ws[WS_SUMG + b];
    float ssq =
        ws[WS_SSW + b * W_ + w] + ws[WS_SST + b * T_ + t] + ws[WS_SSG + b];
    float mu = sum * (1.f / 768.f);
    float var = ssq * (1.f / 768.f) - mu * mu;
    float inv = rsqrtf(var + 1e-5f);
    float logit = inv * (S - mu * C1) + C0;
    out[idx] = 1.f / (1.f + expf(-logit));
    float ls = log_std[w * T_ + t];
    out[B_ * W_ * T_ + idx] = expf(fminf(fmaxf(ls, -4.f), 1.f));
  }
}

}  // namespace

extern "C" void kernel_launch(void* const* d_in, const int* in_sizes, int n_in,
                              void* d_out, int out_size, void* d_ws,
                              size_t ws_size, hipStream_t stream) {
  (void)in_sizes; (void)n_in; (void)out_size; (void)ws_size;
  const float* task_obs        = (const float*)d_in[0];
  const float* worker_loads    = (const float*)d_in[1];
  const float* worker_profiles = (const float*)d_in[2];
  const float* global_context  = (const float*)d_in[3];
  const float* valid_mask      = (const float*)d_in[4];
  const float* te_w1  = (const float*)d_in[5];
  const float* te_b1  = (const float*)d_in[6];
  const float* te_w2  = (const float*)d_in[7];
  const float* te_b2  = (const float*)d_in[8];
  const float* wle_w1 = (const float*)d_in[9];
  const float* wle_b1 = (const float*)d_in[10];
  const float* wle_w2 = (const float*)d_in[11];
  const float* wle_b2 = (const float*)d_in[12];
  const float* wpe_w1 = (const float*)d_in[13];
  const float* wpe_b1 = (const float*)d_in[14];
  const float* wpe_w2 = (const float*)d_in[15];
  const float* wpe_b2 = (const float*)d_in[16];
  const float* ft_w   = (const float*)d_in[17];
  const float* ft_b   = (const float*)d_in[18];
  const float* ft_g   = (const float*)d_in[19];
  const float* ft_bt  = (const float*)d_in[20];
  const float* fw_w   = (const float*)d_in[21];
  const float* fw_b   = (const float*)d_in[22];
  const float* fw_g   = (const float*)d_in[23];
  const float* fw_bt  = (const float*)d_in[24];
  const float* g_w1   = (const float*)d_in[25];
  const float* g_b1   = (const float*)d_in[26];
  const float* g_w2   = (const float*)d_in[27];
  const float* g_b2   = (const float*)d_in[28];
  const float* fn_g   = (const float*)d_in[29];
  const float* fn_b   = (const float*)d_in[30];
  const float* actor_w = (const float*)d_in[31];
  const float* actor_b = (const float*)d_in[32];
  const float* log_std = (const float*)d_in[33];
  const float* vu_w1  = (const float*)d_in[34];
  const float* vu_b1  = (const float*)d_in[35];
  const float* vu_w2  = (const float*)d_in[36];
  const float* vu_b2  = (const float*)d_in[37];
  const float* vc_w1  = (const float*)d_in[38];
  const float* vc_b1  = (const float*)d_in[39];
  const float* vc_w2  = (const float*)d_in[40];
  const float* vc_b2  = (const float*)d_in[41];
  float* ws = (float*)d_ws;
  uint4* wpk = (uint4*)(ws + WS_PK);
  float* out = (float*)d_out;

  hipLaunchKernelGGL(pack_kernel, dim3(PK_TOTAL / 256), dim3(256), 0, stream,
                     te_w1, te_w2, ft_w, wle_w1, wle_w2, wpe_w1, wpe_w2, fw_w,
                     g_w1, g_w2, vu_w1, vc_w1, wpk);
  hipLaunchKernelGGL(enc_kernel, dim3(161), dim3(512), 0, stream, task_obs,
                     worker_loads, worker_profiles, global_context, valid_mask,
                     te_b1, te_b2, wle_b1, wle_b2, wpe_b1, wpe_b2, ft_b, ft_g,
                     ft_bt, fw_b, fw_g, fw_bt, g_b1, g_b2, fn_g, fn_b, actor_w,
                     actor_b, (const uint4*)wpk, ws);
  hipLaunchKernelGGL(head_kernel, dim3(272), dim3(512), 0, stream, valid_mask,
                     log_std, vu_b1, vu_b2, vc_b1, vc_b2, vu_w2, vc_w2,
                     (const uint4*)wpk, (const float*)ws, out);
}